// Round 4
// baseline (2013.759 us; speedup 1.0000x reference)
//
#include <hip/hip_runtime.h>

typedef unsigned int uint;
typedef short bf16x8 __attribute__((ext_vector_type(8)));
typedef float f32x4 __attribute__((ext_vector_type(4)));

// ---------- bf16 helpers (bit-level, RNE) ----------
__device__ __forceinline__ unsigned short f2b(float f) {
    uint u = __builtin_bit_cast(uint, f);
    u += 0x7fffu + ((u >> 16) & 1u);
    return (unsigned short)(u >> 16);
}
__device__ __forceinline__ float b2f(unsigned short h) {
    uint u = ((uint)h) << 16;
    return __builtin_bit_cast(float, u);
}

// ---------- fast tanh-gelu ----------
__device__ __forceinline__ float fast_gelu(float v) {
    float s  = v * v;
    float t2 = __builtin_fmaf(0.044715f * s, v, v);     // v + 0.044715 v^3
    float e  = __expf(-1.5957691216f * t2);             // exp(-2*0.79788456*t2)
    return v * __builtin_amdgcn_rcpf(1.0f + e);
}

// ---------- weight prep ----------
__global__ __launch_bounds__(256) void convert_bf16_kernel(const float* __restrict__ src,
                                                           unsigned short* __restrict__ dst, int n) {
    int idx = blockIdx.x * 256 + threadIdx.x;
    if (idx < n) dst[idx] = f2b(src[idx]);
}

// src is (K, N) row-major; dst is (N, K) row-major (i.e. B^T), bf16.
__global__ __launch_bounds__(256) void transpose_to_bf16_kernel(const float* __restrict__ src,
                                                                unsigned short* __restrict__ dst,
                                                                int K, int N) {
    long long idx = (long long)blockIdx.x * 256 + threadIdx.x;
    if (idx >= (long long)K * N) return;
    int k = (int)(idx / N);
    int n = (int)(idx % N);
    dst[(long long)n * K + k] = f2b(src[idx]);
}

// ---------- im2col: input (B,C,H,W) -> A (16384, 768) bf16, k = c*256+p*16+q ----------
__global__ __launch_bounds__(256) void im2col_kernel(const float* __restrict__ in,
                                                     unsigned short* __restrict__ out) {
    long long idx = (long long)blockIdx.x * 256 + threadIdx.x; // < 16384*768
    int k = (int)(idx % 768);
    int n = (int)(idx / 768);
    int b = n >> 10, t = n & 1023;
    int hp = t >> 5, wp = t & 31;
    int c = k >> 8, rm = k & 255;
    int p = rm >> 4, q = rm & 15;
    long long src = (((long long)(b * 3 + c) * 512) + hp * 16 + p) * 512 + wp * 16 + q;
    out[idx] = f2b(in[src]);
}

// ---------- LayerNorm + sinusoidal PE -> bf16 ----------
__global__ __launch_bounds__(256) void ln_pe_kernel(const float* __restrict__ xe,
                                                    const float* __restrict__ g,
                                                    const float* __restrict__ bb,
                                                    unsigned short* __restrict__ xb) {
    int row = blockIdx.x;            // 0..16383
    int pos = row & 1023;
    const float* xr = xe + (long long)row * 768;
    float v0 = xr[threadIdx.x];
    float v1 = xr[threadIdx.x + 256];
    float v2 = xr[threadIdx.x + 512];
    float s = v0 + v1 + v2;
    float sq = v0 * v0 + v1 * v1 + v2 * v2;
    for (int o = 32; o > 0; o >>= 1) {
        s  += __shfl_down(s, o, 64);
        sq += __shfl_down(sq, o, 64);
    }
    __shared__ float ps[4], pq[4];
    int w = threadIdx.x >> 6, lane = threadIdx.x & 63;
    if (lane == 0) { ps[w] = s; pq[w] = sq; }
    __syncthreads();
    float ts = ps[0] + ps[1] + ps[2] + ps[3];
    float tq = pq[0] + pq[1] + pq[2] + pq[3];
    float mean = ts * (1.0f / 768.0f);
    float var  = tq * (1.0f / 768.0f) - mean * mean;
    float inv  = rsqrtf(var + 1e-5f);
    #pragma unroll
    for (int dd = 0; dd < 3; dd++) {
        int d = threadIdx.x + dd * 256;
        float val = (dd == 0) ? v0 : (dd == 1) ? v1 : v2;
        float y = (val - mean) * inv * g[d] + bb[d];
        float freq = __expf(-(float)(d & ~1) * (9.210340371976184f / 768.0f));
        float ang = (float)pos * freq;
        y += (d & 1) ? cosf(ang) : sinf(ang);
        xb[(long long)row * 768 + d] = f2b(y);
    }
}

// ---------- 128x128 bf16 MFMA GEMM, NO LDS: direct global->register fragments ----------
// Staging-path ablation: three LDS-staged schedules all pinned at 26% MfmaUtil, ~5600
// cyc/tile of unexplained stall. Here每 MFMA fragment is loaded straight from global
// (A row-major, BT row-major -> k-contiguous 16 B per lane; a wave-load = 16 rows x
// 64 B segments). No barriers, no waitcnt, no LDS: occupancy-driven latency hiding
// (grid 3072 for FF1, ~150 VGPR, 0 LDS -> ~6-8 blocks/CU). Intra-block reuse lost vs
// LDS is only 2x/operand at 128^2 (L1/L2 absorb). 2-deep manual pipeline with
// statically-named register sets (rule 20: no runtime-indexed frag arrays).
__global__ __launch_bounds__(256) void gemm128d_kernel(const unsigned short* __restrict__ A,
                                                       const unsigned short* __restrict__ BT,
                                                       const float* __restrict__ bias,
                                                       const unsigned short* __restrict__ residB,
                                                       float* __restrict__ outF,
                                                       unsigned short* __restrict__ outB,
                                                       int M, int N, int K, int ldb,
                                                       int epi, int accumF) {
    // ---- XCD swizzle: id = 8*s + xcd; requires (M/128) % 8 == 0 (holds: 128)
    const int nX = N >> 7;                    // N/128
    int id = blockIdx.x;
    int xcd = id & 7;
    int sq_ = id >> 3;
    int bx = sq_ % nX;
    int by = (sq_ / nX) * 8 + xcd;
    const int m0 = by * 128, n0 = bx * 128;

    const int tid = threadIdx.x;
    const int w = tid >> 6, lane = tid & 63;
    const int wm = (w >> 1) * 64, wn = (w & 1) * 64;   // 2x2 wave grid, 64x64 each
    const int quad = lane >> 4, l15 = lane & 15;

    const long long lK = K, lL = ldb;
    // lane's fragment base: row (m0+wm+l15), k-offset quad*8 (16 B of the 32-wide k-step)
    const unsigned short* Ar = A  + (long long)(m0 + wm + l15) * lK + quad * 8;
    const unsigned short* Br = BT + (long long)(n0 + wn + l15) * lL + quad * 8;

    f32x4 acc[4][4] = {};
    bf16x8 a0[4], b0[4], a1[4], b1[4];

#define LD(Aset, Bset, kk) { \
    _Pragma("unroll") for (int i = 0; i < 4; i++) \
        Aset[i] = *(const bf16x8*)(Ar + (long long)i * 16 * lK + (kk)); \
    _Pragma("unroll") for (int j = 0; j < 4; j++) \
        Bset[j] = *(const bf16x8*)(Br + (long long)j * 16 * lL + (kk)); }
#define FM(Aset, Bset) { \
    _Pragma("unroll") for (int i = 0; i < 4; i++) \
    _Pragma("unroll") for (int j = 0; j < 4; j++) \
        acc[i][j] = __builtin_amdgcn_mfma_f32_16x16x32_bf16(Aset[i], Bset[j], acc[i][j], 0, 0, 0); }

    const int KS = K >> 5;                    // k-steps of 32; even (K % 64 == 0)
    LD(a0, b0, 0);
    for (int ks = 0; ks + 2 < KS; ks += 2) {
        LD(a1, b1, (ks + 1) * 32);
        FM(a0, b0);
        LD(a0, b0, (ks + 2) * 32);
        FM(a1, b1);
    }
    LD(a1, b1, (KS - 1) * 32);
    FM(a0, b0);
    FM(a1, b1);
#undef LD
#undef FM

    // ---- epilogue: v = acc (+ bias); epi==1 -> gelu; accumF -> +outF; residB -> +resid
    const int r0 = quad * 4;
    #pragma unroll
    for (int i = 0; i < 4; i++) {
        #pragma unroll
        for (int j = 0; j < 4; j++) {
            int gn = n0 + wn + j * 16 + l15;
            float bv = bias ? bias[gn] : 0.0f;
            #pragma unroll
            for (int r = 0; r < 4; r++) {
                int gm = m0 + wm + i * 16 + r0 + r;
                float v = acc[i][j][r] + bv;
                if (epi == 1) v = fast_gelu(v);
                long long off = (long long)gm * N + gn;
                if (accumF) v += outF[off];
                if (residB) v += b2f(residB[off]);
                if (outF) outF[off] = v;
                if (outB) outB[off] = f2b(v);
            }
        }
    }
}

// ---------- windowed attention: one block per (b, window, head), 52 KB LDS ----------
__global__ __launch_bounds__(256) void attn_kernel(const unsigned short* __restrict__ qkv,
                                                   unsigned short* __restrict__ o) {
    __shared__ float qs[64 * 65], ks[64 * 65], vs[64 * 65];  // qs reused for probs
    __shared__ float pmax[4 * 64], psum[4 * 64];
    int blk = blockIdx.x;                 // b*16*12 + w*12 + h
    int h = blk % 12;
    int bw = blk / 12;
    int wi = bw % 16, b = bw / 16;
    int rowBase = b * 1024 + wi * 64;
    int tid = threadIdx.x;

    int lr = tid >> 2, c0 = (tid & 3) * 16;
    const unsigned short* src = qkv + (long long)(rowBase + lr) * 2304 + h * 64 + c0;
    #pragma unroll
    for (int j = 0; j < 16; j++) {
        qs[lr * 65 + c0 + j] = b2f(src[j]);
        ks[lr * 65 + c0 + j] = b2f(src[768 + j]);
        vs[lr * 65 + c0 + j] = b2f(src[1536 + j]);
    }
    __syncthreads();

    int r = tid & 63, cg = tid >> 6;
    float svals[16] = {};
    for (int kk = 0; kk < 64; kk++) {
        float qv = qs[r * 65 + kk];                    // per-lane, 2-way bank alias (free)
        #pragma unroll
        for (int j = 0; j < 16; j++)
            svals[j] += qv * ks[(cg * 16 + j) * 65 + kk];   // wave-uniform broadcast
    }
    float smax = -1e30f;
    #pragma unroll
    for (int j = 0; j < 16; j++) {
        svals[j] *= 0.125f;
        smax = fmaxf(smax, svals[j]);
    }
    pmax[cg * 64 + r] = smax;
    __syncthreads();   // all qs(Q) reads done; qs reusable as prob buffer
    float m = fmaxf(fmaxf(pmax[r], pmax[64 + r]), fmaxf(pmax[128 + r], pmax[192 + r]));
    float lsum = 0.0f;
    #pragma unroll
    for (int j = 0; j < 16; j++) {
        float e = __expf(svals[j] - m);
        qs[r * 65 + cg * 16 + j] = e;
        lsum += e;
    }
    psum[cg * 64 + r] = lsum;
    __syncthreads();
    float inv = __builtin_amdgcn_rcpf(psum[r] + psum[64 + r] + psum[128 + r] + psum[192 + r]);

    float oacc[16] = {};
    for (int c = 0; c < 64; c++) {
        float pv = qs[r * 65 + c];
        #pragma unroll
        for (int j = 0; j < 16; j++)
            oacc[j] += pv * vs[c * 65 + cg * 16 + j];       // wave-uniform broadcast
    }
    unsigned short* dst = o + (long long)(rowBase + r) * 768 + h * 64 + cg * 16;
    #pragma unroll
    for (int j = 0; j < 16; j++) dst[j] = f2b(oacc[j] * inv);
}

extern "C" void kernel_launch(void* const* d_in, const int* in_sizes, int n_in,
                              void* d_out, int out_size, void* d_ws, size_t ws_size,
                              hipStream_t stream) {
    const float* input   = (const float*)d_in[0];
    const float* patch_w = (const float*)d_in[1];
    const float* patch_b = (const float*)d_in[2];
    const float* ln_g    = (const float*)d_in[3];
    const float* ln_b    = (const float*)d_in[4];
    const float* qkv_w   = (const float*)d_in[5];
    const float* qkv_b   = (const float*)d_in[6];
    const float* proj_w  = (const float*)d_in[7];
    const float* proj_b  = (const float*)d_in[8];
    const float* ff1_w   = (const float*)d_in[9];
    const float* ff1_b   = (const float*)d_in[10];
    const float* ff2_w   = (const float*)d_in[11];
    const float* ff2_b   = (const float*)d_in[12];
    float* out = (float*)d_out;

    const int MN = 16384;   // B*N tokens
    const int D = 768, F = 3072, TD = 2304;
    const int NY = MN / 128;  // 128 row-blocks (divisible by 8)

    // ---- workspace layout: 83,165,184 uint16 = 166.33 MB (proven to fit) ----
    unsigned short* wPatch = (unsigned short*)d_ws;            // (768,768)
    unsigned short* wQkvT  = wPatch + 589824;                  // (2304,768)
    unsigned short* wProjT = wQkvT + 1769472;                  // (768,768)
    unsigned short* wFf1T  = wProjT + 589824;                  // (3072,768)
    unsigned short* wFf2T  = wFf1T + 2359296;                  // (768,3072)
    unsigned short* bigBuf = wFf2T + 2359296;                  // 50331648: im2col -> h -> qkv -> h2
    unsigned short* xid    = bigBuf + 50331648;                // 12582912: identity -> x2 bf16
    unsigned short* t0     = xid + 12582912;                   // 12582912: y / o bf16
    // d_out (f32, 16384x768): xe (patch GEMM -> LN), then final output

    // ---- weight prep ----
    convert_bf16_kernel<<<(589824 + 255) / 256, 256, 0, stream>>>(patch_w, wPatch, 589824);
    transpose_to_bf16_kernel<<<(1769472 + 255) / 256, 256, 0, stream>>>(qkv_w, wQkvT, D, TD);
    transpose_to_bf16_kernel<<<(589824 + 255) / 256, 256, 0, stream>>>(proj_w, wProjT, D, D);
    transpose_to_bf16_kernel<<<(2359296 + 255) / 256, 256, 0, stream>>>(ff1_w, wFf1T, D, F);
    transpose_to_bf16_kernel<<<(2359296 + 255) / 256, 256, 0, stream>>>(ff2_w, wFf2T, F, D);

    // ---- pipeline ----
    im2col_kernel<<<(MN * 768) / 256, 256, 0, stream>>>(input, bigBuf);

    // G1: xe = im2col @ patch_w^T + patch_b  -> d_out (f32)
    gemm128d_kernel<<<(D / 128) * NY, 256, 0, stream>>>(bigBuf, wPatch, patch_b, nullptr,
                                                        out, nullptr, MN, D, 768, 768, 0, 0);
    // LN + PE -> xid (bf16 identity + GEMM input)
    ln_pe_kernel<<<MN, 256, 0, stream>>>(out, ln_g, ln_b, xid);

    // FF#1: h = gelu(xid @ ff1 + b1) -> bigBuf (bf16, 100.7 MB)
    gemm128d_kernel<<<(F / 128) * NY, 256, 0, stream>>>(xid, wFf1T, ff1_b, nullptr,
                                                        nullptr, bigBuf, MN, F, 768, 768, 1, 0);
    // y = h @ ff2 + b2 -> t0 (bf16)
    gemm128d_kernel<<<(D / 128) * NY, 256, 0, stream>>>(bigBuf, wFf2T, ff2_b, nullptr,
                                                        nullptr, t0, MN, D, F, F, 0, 0);
    // qkv = y @ qkv_w + qkv_b -> bigBuf (bf16, 75.5 MB; h dead)
    gemm128d_kernel<<<(TD / 128) * NY, 256, 0, stream>>>(t0, wQkvT, qkv_b, nullptr,
                                                         nullptr, bigBuf, MN, TD, 768, 768, 0, 0);
    // attention -> o (bf16) into t0
    attn_kernel<<<16 * 16 * 12, 256, 0, stream>>>(bigBuf, t0);

    // x2 = o @ proj + proj_b + identity(xid) -> xid (bf16; in-place per-element safe)
    gemm128d_kernel<<<(D / 128) * NY, 256, 0, stream>>>(t0, wProjT, proj_b, xid,
                                                        nullptr, xid, MN, D, 768, 768, 0, 0);

    // FF#2: h2 = gelu(x2 @ ff1 + b1) -> bigBuf (qkv dead)
    gemm128d_kernel<<<(F / 128) * NY, 256, 0, stream>>>(xid, wFf1T, ff1_b, nullptr,
                                                        nullptr, bigBuf, MN, F, 768, 768, 1, 0);
    // out = h2 @ ff2 + b2 + x2(bf16 resid)  (f32, final)
    gemm128d_kernel<<<(D / 128) * NY, 256, 0, stream>>>(bigBuf, wFf2T, ff2_b, xid,
                                                        out, nullptr, MN, D, F, F, 0, 0);
}

// Round 5
// 947.218 us; speedup vs baseline: 2.1260x; 2.1260x over previous
//
#include <hip/hip_runtime.h>

typedef unsigned int uint;
typedef short bf16x8 __attribute__((ext_vector_type(8)));
typedef float f32x4 __attribute__((ext_vector_type(4)));

// ---------- bf16 helpers (bit-level, RNE) ----------
__device__ __forceinline__ unsigned short f2b(float f) {
    uint u = __builtin_bit_cast(uint, f);
    u += 0x7fffu + ((u >> 16) & 1u);
    return (unsigned short)(u >> 16);
}
__device__ __forceinline__ float b2f(unsigned short h) {
    uint u = ((uint)h) << 16;
    return __builtin_bit_cast(float, u);
}

// ---------- fast tanh-gelu ----------
__device__ __forceinline__ float fast_gelu(float v) {
    float s  = v * v;
    float t2 = __builtin_fmaf(0.044715f * s, v, v);     // v + 0.044715 v^3
    float e  = __expf(-1.5957691216f * t2);             // exp(-2*0.79788456*t2)
    return v * __builtin_amdgcn_rcpf(1.0f + e);
}

// ---------- async global->LDS, 16B per lane (wave-uniform LDS base + lane*16) ----------
__device__ __forceinline__ void gl_lds16(const unsigned short* g, unsigned short* l) {
    __builtin_amdgcn_global_load_lds(
        reinterpret_cast<const __attribute__((address_space(1))) unsigned int*>(
            reinterpret_cast<uintptr_t>(g)),
        reinterpret_cast<__attribute__((address_space(3))) unsigned int*>(
            reinterpret_cast<uintptr_t>(l)),
        16, 0, 0);
}

// ---------- weight prep ----------
__global__ __launch_bounds__(256) void convert_bf16_kernel(const float* __restrict__ src,
                                                           unsigned short* __restrict__ dst, int n) {
    int idx = blockIdx.x * 256 + threadIdx.x;
    if (idx < n) dst[idx] = f2b(src[idx]);
}

// src is (K, N) row-major; dst is (N, K) row-major (i.e. B^T), bf16.
__global__ __launch_bounds__(256) void transpose_to_bf16_kernel(const float* __restrict__ src,
                                                                unsigned short* __restrict__ dst,
                                                                int K, int N) {
    long long idx = (long long)blockIdx.x * 256 + threadIdx.x;
    if (idx >= (long long)K * N) return;
    int k = (int)(idx / N);
    int n = (int)(idx % N);
    dst[(long long)n * K + k] = f2b(src[idx]);
}

// ---------- im2col: input (B,C,H,W) -> A (16384, 768) bf16, k = c*256+p*16+q ----------
__global__ __launch_bounds__(256) void im2col_kernel(const float* __restrict__ in,
                                                     unsigned short* __restrict__ out) {
    long long idx = (long long)blockIdx.x * 256 + threadIdx.x; // < 16384*768
    int k = (int)(idx % 768);
    int n = (int)(idx / 768);
    int b = n >> 10, t = n & 1023;
    int hp = t >> 5, wp = t & 31;
    int c = k >> 8, rm = k & 255;
    int p = rm >> 4, q = rm & 15;
    long long src = (((long long)(b * 3 + c) * 512) + hp * 16 + p) * 512 + wp * 16 + q;
    out[idx] = f2b(in[src]);
}

// ---------- LayerNorm + sinusoidal PE -> bf16 ----------
__global__ __launch_bounds__(256) void ln_pe_kernel(const float* __restrict__ xe,
                                                    const float* __restrict__ g,
                                                    const float* __restrict__ bb,
                                                    unsigned short* __restrict__ xb) {
    int row = blockIdx.x;            // 0..16383
    int pos = row & 1023;
    const float* xr = xe + (long long)row * 768;
    float v0 = xr[threadIdx.x];
    float v1 = xr[threadIdx.x + 256];
    float v2 = xr[threadIdx.x + 512];
    float s = v0 + v1 + v2;
    float sq = v0 * v0 + v1 * v1 + v2 * v2;
    for (int o = 32; o > 0; o >>= 1) {
        s  += __shfl_down(s, o, 64);
        sq += __shfl_down(sq, o, 64);
    }
    __shared__ float ps[4], pq[4];
    int w = threadIdx.x >> 6, lane = threadIdx.x & 63;
    if (lane == 0) { ps[w] = s; pq[w] = sq; }
    __syncthreads();
    float ts = ps[0] + ps[1] + ps[2] + ps[3];
    float tq = pq[0] + pq[1] + pq[2] + pq[3];
    float mean = ts * (1.0f / 768.0f);
    float var  = tq * (1.0f / 768.0f) - mean * mean;
    float inv  = rsqrtf(var + 1e-5f);
    #pragma unroll
    for (int dd = 0; dd < 3; dd++) {
        int d = threadIdx.x + dd * 256;
        float val = (dd == 0) ? v0 : (dd == 1) ? v1 : v2;
        float y = (val - mean) * inv * g[d] + bb[d];
        float freq = __expf(-(float)(d & ~1) * (9.210340371976184f / 768.0f));
        float ang = (float)pos * freq;
        y += (d & 1) ? cosf(ang) : sinf(ang);
        xb[(long long)row * 768 + d] = f2b(y);
    }
}

// ---------- 256x256 bf16 MFMA GEMM, BK=64, tile-barrier-only free-run pipeline ----------
// R4 diagnosis: per-phase barriers lockstep all 8 waves -> LDS-read pipe (2304 cyc/tile)
// and MFMA pipe (2483 cyc/tile) alternate instead of overlap (serial sum ~6100 = measured).
// This version: only TWO barriers per K-tile. Per tile each wave issues ALL 24
// ds_read_b128 up front (LDS FIFO drains in background), then MFMA quadrants gated by
// counted lgkm (in-order DS retirement): WAITL(12)->q00, WAITL(8)->q01, WAITL(0)->q11,q10.
// Mid-tile BAR after WAITL(0) (all reads of buf b retired) protects restaging s+2 -> b;
// q11/q10 (register-only) run after it, hiding the staging loads' HBM latency.
// WAITV(8) + BAR per tile: counted vmem pipeline, never drained to 0 in the loop.
// vmem FIFO: prologue stages t0,t1 (16 loads), WAITV(8) retires t0; steady: +8/iter,
// WAITV(8) retires tile s+1's 8. Tail iterations stage clamped dummy loads (dead slots).
// LDS slot (row,c8) holds global (row, c8^(row&7)); swizzle applied on the fetch side.
// All fragment reads are inline-asm ds_read_b128 (invisible to SIInsertWaitcnts -> no
// compiler vmcnt(0) drains); rule-18 sched_barrier(0) after each counted lgkm wait.
__global__ __launch_bounds__(512) void gemm256_kernel(const unsigned short* __restrict__ A,
                                                      const unsigned short* __restrict__ BT,
                                                      const float* __restrict__ bias,
                                                      const unsigned short* __restrict__ residB,
                                                      float* __restrict__ outF,
                                                      unsigned short* __restrict__ outB,
                                                      int M, int N, int K, int ldb,
                                                      int epi, int accumF) {
    __shared__ __align__(16) unsigned short As[2][256 * 64];   // 64 KB
    __shared__ __align__(16) unsigned short Bs[2][256 * 64];   // 64 KB

    // ---- XCD swizzle: id = 8*s + xcd; requires (M/256) % 8 == 0 (holds: 64)
    const int nX = N >> 8;                    // N/256
    int id = blockIdx.x;
    int xcd = id & 7;
    int sq_ = id >> 3;
    int bx = sq_ % nX;
    int by = (sq_ / nX) * 8 + xcd;
    const int m0 = by * 256, n0 = bx * 256;

    const int tid = threadIdx.x;
    const int w = tid >> 6, lane = tid & 63;
    const int wr = w >> 2, wc = w & 3;               // 2x4 wave grid
    const int quad = lane >> 4, l15 = lane & 15;
    const int swz = l15 & 7;                         // fragment-row swizzle key

    // ---- staging addressing: thread t -> LDS 16B-unit t (wave-uniform base + lane*16)
    const int row0 = tid >> 3;                       // 0..63
    const int c8   = tid & 7;
    const int gc8  = c8 ^ (row0 & 7);                // (row0+64)&7 == row0&7
    const unsigned short* Ag = A  + (long long)(m0 + row0) * K   + gc8 * 8;
    const unsigned short* Bg = BT + (long long)(n0 + row0) * ldb + gc8 * 8;
    unsigned short* Ad = &As[0][0] + row0 * 64 + c8 * 8;
    unsigned short* Bd = &Bs[0][0] + row0 * 64 + c8 * 8;
    const long long aK64 = (long long)64 * K,  aK128 = (long long)128 * K;
    const long long bL64 = (long long)64 * ldb, bL128 = (long long)128 * ldb;

#define STAGE_A(bsel, h, ks) { \
    const unsigned short* s_ = Ag + (h) * aK128 + (ks); \
    unsigned short* d_ = Ad + (bsel) * 16384 + (h) * 8192; \
    gl_lds16(s_, d_); gl_lds16(s_ + aK64, d_ + 4096); }
#define STAGE_B(bsel, h, ks) { \
    const unsigned short* s_ = Bg + (h) * bL128 + (ks); \
    unsigned short* d_ = Bd + (bsel) * 16384 + (h) * 8192; \
    gl_lds16(s_, d_); gl_lds16(s_ + bL64, d_ + 4096); }

    // ---- fragment LDS byte addresses (buffer 0); per-iter XOR 0x8000 toggles buffer.
    unsigned asB = (unsigned)(uintptr_t)(&As[0][0]);
    unsigned bsB = (unsigned)(uintptr_t)(&Bs[0][0]);
    unsigned aH0 = asB + (unsigned)((wr * 64 + l15) * 128 + ((quad ^ swz) * 16));
    unsigned aH1 = asB + (unsigned)((wr * 64 + l15) * 128 + (((4 + quad) ^ swz) * 16));
    unsigned bH0 = bsB + (unsigned)((wc * 32 + l15) * 128 + ((quad ^ swz) * 16));
    unsigned bH1 = bsB + (unsigned)((wc * 32 + l15) * 128 + (((4 + quad) ^ swz) * 16));

    bf16x8 afA[4][2], afB[4][2], bfr0[2][2], bfr1[2][2];
    f32x4 acc[2][2][4][2] = {};

#define DSR(dst, addr, IMM) \
    asm volatile("ds_read_b128 %0, %1 offset:%2" : "=&v"(dst) : "v"(addr), "i"(IMM))

#define R_A0() { DSR(afA[0][0], aH0, 0);     DSR(afA[1][0], aH0, 2048); \
                 DSR(afA[2][0], aH0, 4096);  DSR(afA[3][0], aH0, 6144); \
                 DSR(afA[0][1], aH1, 0);     DSR(afA[1][1], aH1, 2048); \
                 DSR(afA[2][1], aH1, 4096);  DSR(afA[3][1], aH1, 6144); }
#define R_A1() { DSR(afB[0][0], aH0, 16384); DSR(afB[1][0], aH0, 18432); \
                 DSR(afB[2][0], aH0, 20480); DSR(afB[3][0], aH0, 22528); \
                 DSR(afB[0][1], aH1, 16384); DSR(afB[1][1], aH1, 18432); \
                 DSR(afB[2][1], aH1, 20480); DSR(afB[3][1], aH1, 22528); }
#define R_B0() { DSR(bfr0[0][0], bH0, 0);     DSR(bfr0[1][0], bH0, 2048); \
                 DSR(bfr0[0][1], bH1, 0);     DSR(bfr0[1][1], bH1, 2048); }
#define R_B1() { DSR(bfr1[0][0], bH0, 16384); DSR(bfr1[1][0], bH0, 18432); \
                 DSR(bfr1[0][1], bH1, 16384); DSR(bfr1[1][1], bH1, 18432); }

#define MFMA16(AF, BF, qm, qn) { \
    __builtin_amdgcn_s_setprio(1); \
    _Pragma("unroll") for (int mf_ = 0; mf_ < 4; mf_++) \
    _Pragma("unroll") for (int nf_ = 0; nf_ < 2; nf_++) { \
      acc[qm][qn][mf_][nf_] = __builtin_amdgcn_mfma_f32_16x16x32_bf16(AF[mf_][0], BF[nf_][0], acc[qm][qn][mf_][nf_], 0, 0, 0); \
      acc[qm][qn][mf_][nf_] = __builtin_amdgcn_mfma_f32_16x16x32_bf16(AF[mf_][1], BF[nf_][1], acc[qm][qn][mf_][nf_], 0, 0, 0); \
    } \
    __builtin_amdgcn_s_setprio(0); }

#define BAR() { asm volatile("" ::: "memory"); __builtin_amdgcn_s_barrier(); asm volatile("" ::: "memory"); }
#define WAITL(n) { asm volatile("s_waitcnt lgkmcnt(" #n ")" ::: "memory"); __builtin_amdgcn_sched_barrier(0); }
#define WAITV(n) { asm volatile("s_waitcnt vmcnt(" #n ")" ::: "memory"); }

    const int NT = K >> 6;                    // K-tiles (>= 2 for all call sites)

    // ---- prologue: stage t0 -> buf0, t1 -> buf1; retire t0; sync
    STAGE_A(0, 0, 0);
    STAGE_A(0, 1, 0);
    STAGE_B(0, 0, 0);
    STAGE_B(0, 1, 0);
    STAGE_A(1, 0, 64);
    STAGE_A(1, 1, 64);
    STAGE_B(1, 0, 64);
    STAGE_B(1, 1, 64);
    WAITV(8);                                 // t0's 8 loads retired (t1's 8 in flight)
    BAR();

    for (int s = 0; s < NT; s++) {
        const int b = s & 1;
        const int ks2 = (s + 2 < NT) ? (s + 2) * 64 : 0;   // dummy loads keep FIFO exact

        // ---- issue ALL 24 fragment reads for tile s from buf b (LDS FIFO drains in bg)
        R_A0();                               // reads 1-8
        R_B0();                               // reads 9-12
        R_B1();                               // reads 13-16
        R_A1();                               // reads 17-24
        // ---- MFMA quadrants gated by counted lgkm; reads overlap MFMA in-wave & cross-wave
        WAITL(12);                            // afA + bfr0 ready
        MFMA16(afA, bfr0, 0, 0);
        WAITL(8);                             // bfr1 ready
        MFMA16(afA, bfr1, 0, 1);
        WAITL(0);                             // afB ready; ALL reads of buf b retired
        BAR();                                // -> safe to restage buf b
        STAGE_A(b, 0, ks2);                   // tile s+2 -> buf b (8 loads)
        STAGE_A(b, 1, ks2);
        STAGE_B(b, 0, ks2);
        STAGE_B(b, 1, ks2);
        MFMA16(afB, bfr1, 1, 1);              // register-only: hides staging HBM latency
        MFMA16(afB, bfr0, 1, 0);
        WAITV(8);                             // retire tile s+1's 8 loads (long done)
        BAR();                                // all waves: buf bn (tile s+1) readable
        aH0 ^= 32768u; aH1 ^= 32768u; bH0 ^= 32768u; bH1 ^= 32768u;
    }
    asm volatile("s_waitcnt vmcnt(0) lgkmcnt(0)" ::: "memory");  // drain tail dummies
    __builtin_amdgcn_sched_barrier(0);

    // ---- epilogue: v = acc (+ bias); epi==1 -> gelu; accumF -> +outF; residB -> +resid
    const int r0 = quad * 4;
    #pragma unroll
    for (int qm = 0; qm < 2; qm++)
    #pragma unroll
    for (int qn = 0; qn < 2; qn++)
    #pragma unroll
    for (int mf = 0; mf < 4; mf++)
    #pragma unroll
    for (int nf = 0; nf < 2; nf++) {
        int gn = n0 + qn * 128 + wc * 32 + nf * 16 + l15;
        float bv = bias ? bias[gn] : 0.0f;
        #pragma unroll
        for (int r = 0; r < 4; r++) {
            int gm = m0 + qm * 128 + wr * 64 + mf * 16 + r0 + r;
            float v = acc[qm][qn][mf][nf][r] + bv;
            if (epi == 1) v = fast_gelu(v);
            long long off = (long long)gm * N + gn;
            if (accumF) v += outF[off];
            if (residB) v += b2f(residB[off]);
            if (outF) outF[off] = v;
            if (outB) outB[off] = f2b(v);
        }
    }
#undef STAGE_A
#undef STAGE_B
#undef DSR
#undef R_A0
#undef R_A1
#undef R_B0
#undef R_B1
#undef MFMA16
#undef BAR
#undef WAITL
#undef WAITV
}

// ---------- windowed attention: one block per (b, window, head), 52 KB LDS ----------
__global__ __launch_bounds__(256) void attn_kernel(const unsigned short* __restrict__ qkv,
                                                   unsigned short* __restrict__ o) {
    __shared__ float qs[64 * 65], ks[64 * 65], vs[64 * 65];  // qs reused for probs
    __shared__ float pmax[4 * 64], psum[4 * 64];
    int blk = blockIdx.x;                 // b*16*12 + w*12 + h
    int h = blk % 12;
    int bw = blk / 12;
    int wi = bw % 16, b = bw / 16;
    int rowBase = b * 1024 + wi * 64;
    int tid = threadIdx.x;

    int lr = tid >> 2, c0 = (tid & 3) * 16;
    const unsigned short* src = qkv + (long long)(rowBase + lr) * 2304 + h * 64 + c0;
    #pragma unroll
    for (int j = 0; j < 16; j++) {
        qs[lr * 65 + c0 + j] = b2f(src[j]);
        ks[lr * 65 + c0 + j] = b2f(src[768 + j]);
        vs[lr * 65 + c0 + j] = b2f(src[1536 + j]);
    }
    __syncthreads();

    int r = tid & 63, cg = tid >> 6;
    float svals[16] = {};
    for (int kk = 0; kk < 64; kk++) {
        float qv = qs[r * 65 + kk];                    // per-lane, 2-way bank alias (free)
        #pragma unroll
        for (int j = 0; j < 16; j++)
            svals[j] += qv * ks[(cg * 16 + j) * 65 + kk];   // wave-uniform broadcast
    }
    float smax = -1e30f;
    #pragma unroll
    for (int j = 0; j < 16; j++) {
        svals[j] *= 0.125f;
        smax = fmaxf(smax, svals[j]);
    }
    pmax[cg * 64 + r] = smax;
    __syncthreads();   // all qs(Q) reads done; qs reusable as prob buffer
    float m = fmaxf(fmaxf(pmax[r], pmax[64 + r]), fmaxf(pmax[128 + r], pmax[192 + r]));
    float lsum = 0.0f;
    #pragma unroll
    for (int j = 0; j < 16; j++) {
        float e = __expf(svals[j] - m);
        qs[r * 65 + cg * 16 + j] = e;
        lsum += e;
    }
    psum[cg * 64 + r] = lsum;
    __syncthreads();
    float inv = __builtin_amdgcn_rcpf(psum[r] + psum[64 + r] + psum[128 + r] + psum[192 + r]);

    float oacc[16] = {};
    for (int c = 0; c < 64; c++) {
        float pv = qs[r * 65 + c];
        #pragma unroll
        for (int j = 0; j < 16; j++)
            oacc[j] += pv * vs[c * 65 + cg * 16 + j];       // wave-uniform broadcast
    }
    unsigned short* dst = o + (long long)(rowBase + r) * 768 + h * 64 + cg * 16;
    #pragma unroll
    for (int j = 0; j < 16; j++) dst[j] = f2b(oacc[j] * inv);
}

extern "C" void kernel_launch(void* const* d_in, const int* in_sizes, int n_in,
                              void* d_out, int out_size, void* d_ws, size_t ws_size,
                              hipStream_t stream) {
    const float* input   = (const float*)d_in[0];
    const float* patch_w = (const float*)d_in[1];
    const float* patch_b = (const float*)d_in[2];
    const float* ln_g    = (const float*)d_in[3];
    const float* ln_b    = (const float*)d_in[4];
    const float* qkv_w   = (const float*)d_in[5];
    const float* qkv_b   = (const float*)d_in[6];
    const float* proj_w  = (const float*)d_in[7];
    const float* proj_b  = (const float*)d_in[8];
    const float* ff1_w   = (const float*)d_in[9];
    const float* ff1_b   = (const float*)d_in[10];
    const float* ff2_w   = (const float*)d_in[11];
    const float* ff2_b   = (const float*)d_in[12];
    float* out = (float*)d_out;

    const int MN = 16384;   // B*N tokens
    const int D = 768, F = 3072, TD = 2304;
    const int NY = MN / 256;  // 64 row-blocks (divisible by 8)

    // ---- workspace layout: 83,165,184 uint16 = 166.33 MB (proven to fit) ----
    unsigned short* wPatch = (unsigned short*)d_ws;            // (768,768)
    unsigned short* wQkvT  = wPatch + 589824;                  // (2304,768)
    unsigned short* wProjT = wQkvT + 1769472;                  // (768,768)
    unsigned short* wFf1T  = wProjT + 589824;                  // (3072,768)
    unsigned short* wFf2T  = wFf1T + 2359296;                  // (768,3072)
    unsigned short* bigBuf = wFf2T + 2359296;                  // 50331648: im2col -> h -> qkv -> h2
    unsigned short* xid    = bigBuf + 50331648;                // 12582912: identity -> x2 bf16
    unsigned short* t0     = xid + 12582912;                   // 12582912: y / o bf16
    // d_out (f32, 16384x768): xe (patch GEMM -> LN), then final output

    // ---- weight prep ----
    convert_bf16_kernel<<<(589824 + 255) / 256, 256, 0, stream>>>(patch_w, wPatch, 589824);
    transpose_to_bf16_kernel<<<(1769472 + 255) / 256, 256, 0, stream>>>(qkv_w, wQkvT, D, TD);
    transpose_to_bf16_kernel<<<(589824 + 255) / 256, 256, 0, stream>>>(proj_w, wProjT, D, D);
    transpose_to_bf16_kernel<<<(2359296 + 255) / 256, 256, 0, stream>>>(ff1_w, wFf1T, D, F);
    transpose_to_bf16_kernel<<<(2359296 + 255) / 256, 256, 0, stream>>>(ff2_w, wFf2T, F, D);

    // ---- pipeline ----
    im2col_kernel<<<(MN * 768) / 256, 256, 0, stream>>>(input, bigBuf);

    // G1: xe = im2col @ patch_w^T + patch_b  -> d_out (f32)
    gemm256_kernel<<<(D / 256) * NY, 512, 0, stream>>>(bigBuf, wPatch, patch_b, nullptr,
                                                       out, nullptr, MN, D, 768, 768, 0, 0);
    // LN + PE -> xid (bf16 identity + GEMM input)
    ln_pe_kernel<<<MN, 256, 0, stream>>>(out, ln_g, ln_b, xid);

    // FF#1: h = gelu(xid @ ff1 + b1) -> bigBuf (bf16, 100.7 MB)
    gemm256_kernel<<<(F / 256) * NY, 512, 0, stream>>>(xid, wFf1T, ff1_b, nullptr,
                                                       nullptr, bigBuf, MN, F, 768, 768, 1, 0);
    // y = h @ ff2 + b2 -> t0 (bf16)
    gemm256_kernel<<<(D / 256) * NY, 512, 0, stream>>>(bigBuf, wFf2T, ff2_b, nullptr,
                                                       nullptr, t0, MN, D, F, F, 0, 0);
    // qkv = y @ qkv_w + qkv_b -> bigBuf (bf16, 75.5 MB; h dead)
    gemm256_kernel<<<(TD / 256) * NY, 512, 0, stream>>>(t0, wQkvT, qkv_b, nullptr,
                                                        nullptr, bigBuf, MN, TD, 768, 768, 0, 0);
    // attention -> o (bf16) into t0
    attn_kernel<<<16 * 16 * 12, 256, 0, stream>>>(bigBuf, t0);

    // x2 = o @ proj + proj_b + identity(xid) -> xid (bf16; in-place per-element safe)
    gemm256_kernel<<<(D / 256) * NY, 512, 0, stream>>>(t0, wProjT, proj_b, xid,
                                                       nullptr, xid, MN, D, 768, 768, 0, 0);

    // FF#2: h2 = gelu(x2 @ ff1 + b1) -> bigBuf (qkv dead)
    gemm256_kernel<<<(F / 256) * NY, 512, 0, stream>>>(xid, wFf1T, ff1_b, nullptr,
                                                       nullptr, bigBuf, MN, F, 768, 768, 1, 0);
    // out = h2 @ ff2 + b2 + x2(bf16 resid)  (f32, final)
    gemm256_kernel<<<(D / 256) * NY, 512, 0, stream>>>(bigBuf, wFf2T, ff2_b, xid,
                                                       out, nullptr, MN, D, F, F, 0, 0);
}

// Round 6
// 894.490 us; speedup vs baseline: 2.2513x; 1.0589x over previous
//
#include <hip/hip_runtime.h>

typedef unsigned int uint;
typedef short bf16x8 __attribute__((ext_vector_type(8)));
typedef float f32x4 __attribute__((ext_vector_type(4)));

// ---------- bf16 helpers (bit-level, RNE) ----------
__device__ __forceinline__ unsigned short f2b(float f) {
    uint u = __builtin_bit_cast(uint, f);
    u += 0x7fffu + ((u >> 16) & 1u);
    return (unsigned short)(u >> 16);
}
__device__ __forceinline__ float b2f(unsigned short h) {
    uint u = ((uint)h) << 16;
    return __builtin_bit_cast(float, u);
}

// ---------- fast tanh-gelu ----------
__device__ __forceinline__ float fast_gelu(float v) {
    float s  = v * v;
    float t2 = __builtin_fmaf(0.044715f * s, v, v);     // v + 0.044715 v^3
    float e  = __expf(-1.5957691216f * t2);             // exp(-2*0.79788456*t2)
    return v * __builtin_amdgcn_rcpf(1.0f + e);
}

// ---------- async global->LDS, 16B per lane (wave-uniform LDS base + lane*16) ----------
__device__ __forceinline__ void gl_lds16(const unsigned short* g, unsigned short* l) {
    __builtin_amdgcn_global_load_lds(
        reinterpret_cast<const __attribute__((address_space(1))) unsigned int*>(
            reinterpret_cast<uintptr_t>(g)),
        reinterpret_cast<__attribute__((address_space(3))) unsigned int*>(
            reinterpret_cast<uintptr_t>(l)),
        16, 0, 0);
}

// ---------- weight prep ----------
__global__ __launch_bounds__(256) void convert_bf16_kernel(const float* __restrict__ src,
                                                           unsigned short* __restrict__ dst, int n) {
    int idx = blockIdx.x * 256 + threadIdx.x;
    if (idx < n) dst[idx] = f2b(src[idx]);
}

// src is (K, N) row-major; dst is (N, K) row-major (i.e. B^T), bf16.
__global__ __launch_bounds__(256) void transpose_to_bf16_kernel(const float* __restrict__ src,
                                                                unsigned short* __restrict__ dst,
                                                                int K, int N) {
    long long idx = (long long)blockIdx.x * 256 + threadIdx.x;
    if (idx >= (long long)K * N) return;
    int k = (int)(idx / N);
    int n = (int)(idx % N);
    dst[(long long)n * K + k] = f2b(src[idx]);
}

// ---------- im2col: input (B,C,H,W) -> A (16384, 768) bf16, k = c*256+p*16+q ----------
__global__ __launch_bounds__(256) void im2col_kernel(const float* __restrict__ in,
                                                     unsigned short* __restrict__ out) {
    long long idx = (long long)blockIdx.x * 256 + threadIdx.x; // < 16384*768
    int k = (int)(idx % 768);
    int n = (int)(idx / 768);
    int b = n >> 10, t = n & 1023;
    int hp = t >> 5, wp = t & 31;
    int c = k >> 8, rm = k & 255;
    int p = rm >> 4, q = rm & 15;
    long long src = (((long long)(b * 3 + c) * 512) + hp * 16 + p) * 512 + wp * 16 + q;
    out[idx] = f2b(in[src]);
}

// ---------- LayerNorm + sinusoidal PE -> bf16 ----------
__global__ __launch_bounds__(256) void ln_pe_kernel(const float* __restrict__ xe,
                                                    const float* __restrict__ g,
                                                    const float* __restrict__ bb,
                                                    unsigned short* __restrict__ xb) {
    int row = blockIdx.x;            // 0..16383
    int pos = row & 1023;
    const float* xr = xe + (long long)row * 768;
    float v0 = xr[threadIdx.x];
    float v1 = xr[threadIdx.x + 256];
    float v2 = xr[threadIdx.x + 512];
    float s = v0 + v1 + v2;
    float sq = v0 * v0 + v1 * v1 + v2 * v2;
    for (int o = 32; o > 0; o >>= 1) {
        s  += __shfl_down(s, o, 64);
        sq += __shfl_down(sq, o, 64);
    }
    __shared__ float ps[4], pq[4];
    int w = threadIdx.x >> 6, lane = threadIdx.x & 63;
    if (lane == 0) { ps[w] = s; pq[w] = sq; }
    __syncthreads();
    float ts = ps[0] + ps[1] + ps[2] + ps[3];
    float tq = pq[0] + pq[1] + pq[2] + pq[3];
    float mean = ts * (1.0f / 768.0f);
    float var  = tq * (1.0f / 768.0f) - mean * mean;
    float inv  = rsqrtf(var + 1e-5f);
    #pragma unroll
    for (int dd = 0; dd < 3; dd++) {
        int d = threadIdx.x + dd * 256;
        float val = (dd == 0) ? v0 : (dd == 1) ? v1 : v2;
        float y = (val - mean) * inv * g[d] + bb[d];
        float freq = __expf(-(float)(d & ~1) * (9.210340371976184f / 768.0f));
        float ang = (float)pos * freq;
        y += (d & 1) ? cosf(ang) : sinf(ang);
        xb[(long long)row * 768 + d] = f2b(y);
    }
}

// ---------- 256x256 bf16 MFMA GEMM, BK=64, 4-phase counted-vmcnt/lgkmcnt pipeline ----------
// (R3 structure: best measured of {R0 drain-loop, R1 compiler-8ph, R3 asm-8ph, R5 free-run}.)
// All fragment LDS loads are inline-asm ds_read_b128 (invisible to SIInsertWaitcnts);
// counted lgkm gating one phase ahead; vmcnt(4) once per K-tile, never drained in-loop.
__global__ __launch_bounds__(512) void gemm256_kernel(const unsigned short* __restrict__ A,
                                                      const unsigned short* __restrict__ BT,
                                                      const float* __restrict__ bias,
                                                      const unsigned short* __restrict__ residB,
                                                      float* __restrict__ outF,
                                                      unsigned short* __restrict__ outB,
                                                      int M, int N, int K, int ldb,
                                                      int epi, int accumF) {
    __shared__ __align__(16) unsigned short As[2][256 * 64];   // 64 KB
    __shared__ __align__(16) unsigned short Bs[2][256 * 64];   // 64 KB

    // ---- XCD swizzle: id = 8*s + xcd; requires (M/256) % 8 == 0 (holds: 64)
    const int nX = N >> 8;                    // N/256
    int id = blockIdx.x;
    int xcd = id & 7;
    int sq_ = id >> 3;
    int bx = sq_ % nX;
    int by = (sq_ / nX) * 8 + xcd;
    const int m0 = by * 256, n0 = bx * 256;

    const int tid = threadIdx.x;
    const int w = tid >> 6, lane = tid & 63;
    const int wr = w >> 2, wc = w & 3;               // 2x4 wave grid
    const int quad = lane >> 4, l15 = lane & 15;
    const int swz = l15 & 7;                         // fragment-row swizzle key

    // ---- staging addressing: thread t -> LDS 16B-unit t (wave-uniform base + lane*16)
    const int row0 = tid >> 3;                       // 0..63
    const int c8   = tid & 7;
    const int gc8  = c8 ^ (row0 & 7);                // (row0+64)&7 == row0&7
    const unsigned short* Ag = A  + (long long)(m0 + row0) * K   + gc8 * 8;
    const unsigned short* Bg = BT + (long long)(n0 + row0) * ldb + gc8 * 8;
    unsigned short* Ad = &As[0][0] + row0 * 64 + c8 * 8;
    unsigned short* Bd = &Bs[0][0] + row0 * 64 + c8 * 8;
    const long long aK64 = (long long)64 * K,  aK128 = (long long)128 * K;
    const long long bL64 = (long long)64 * ldb, bL128 = (long long)128 * ldb;

#define STAGE_A(bsel, h, ks) { \
    const unsigned short* s_ = Ag + (h) * aK128 + (ks); \
    unsigned short* d_ = Ad + (bsel) * 16384 + (h) * 8192; \
    gl_lds16(s_, d_); gl_lds16(s_ + aK64, d_ + 4096); }
#define STAGE_B(bsel, h, ks) { \
    const unsigned short* s_ = Bg + (h) * bL128 + (ks); \
    unsigned short* d_ = Bd + (bsel) * 16384 + (h) * 8192; \
    gl_lds16(s_, d_); gl_lds16(s_ + bL64, d_ + 4096); }

    // ---- fragment LDS byte addresses (buffer 0); per-iter XOR 0x8000 toggles buffer.
    unsigned asB = (unsigned)(uintptr_t)(&As[0][0]);
    unsigned bsB = (unsigned)(uintptr_t)(&Bs[0][0]);
    unsigned aH0 = asB + (unsigned)((wr * 64 + l15) * 128 + ((quad ^ swz) * 16));
    unsigned aH1 = asB + (unsigned)((wr * 64 + l15) * 128 + (((4 + quad) ^ swz) * 16));
    unsigned bH0 = bsB + (unsigned)((wc * 32 + l15) * 128 + ((quad ^ swz) * 16));
    unsigned bH1 = bsB + (unsigned)((wc * 32 + l15) * 128 + (((4 + quad) ^ swz) * 16));

    bf16x8 afA[4][2], afB[4][2], bfr0[2][2], bfr1[2][2];
    f32x4 acc[2][2][4][2] = {};

#define DSR(dst, addr, IMM) \
    asm volatile("ds_read_b128 %0, %1 offset:%2" : "=&v"(dst) : "v"(addr), "i"(IMM))

#define R_A0() { DSR(afA[0][0], aH0, 0);     DSR(afA[1][0], aH0, 2048); \
                 DSR(afA[2][0], aH0, 4096);  DSR(afA[3][0], aH0, 6144); \
                 DSR(afA[0][1], aH1, 0);     DSR(afA[1][1], aH1, 2048); \
                 DSR(afA[2][1], aH1, 4096);  DSR(afA[3][1], aH1, 6144); }
#define R_A1() { DSR(afB[0][0], aH0, 16384); DSR(afB[1][0], aH0, 18432); \
                 DSR(afB[2][0], aH0, 20480); DSR(afB[3][0], aH0, 22528); \
                 DSR(afB[0][1], aH1, 16384); DSR(afB[1][1], aH1, 18432); \
                 DSR(afB[2][1], aH1, 20480); DSR(afB[3][1], aH1, 22528); }
#define R_B0() { DSR(bfr0[0][0], bH0, 0);     DSR(bfr0[1][0], bH0, 2048); \
                 DSR(bfr0[0][1], bH1, 0);     DSR(bfr0[1][1], bH1, 2048); }
#define R_B1() { DSR(bfr1[0][0], bH0, 16384); DSR(bfr1[1][0], bH0, 18432); \
                 DSR(bfr1[0][1], bH1, 16384); DSR(bfr1[1][1], bH1, 18432); }

#define MFMA16(AF, BF, qm, qn) { \
    __builtin_amdgcn_sched_barrier(0); \
    __builtin_amdgcn_s_setprio(1); \
    _Pragma("unroll") for (int mf_ = 0; mf_ < 4; mf_++) \
    _Pragma("unroll") for (int nf_ = 0; nf_ < 2; nf_++) { \
      acc[qm][qn][mf_][nf_] = __builtin_amdgcn_mfma_f32_16x16x32_bf16(AF[mf_][0], BF[nf_][0], acc[qm][qn][mf_][nf_], 0, 0, 0); \
      acc[qm][qn][mf_][nf_] = __builtin_amdgcn_mfma_f32_16x16x32_bf16(AF[mf_][1], BF[nf_][1], acc[qm][qn][mf_][nf_], 0, 0, 0); \
    } \
    __builtin_amdgcn_s_setprio(0); \
    __builtin_amdgcn_sched_barrier(0); }

#define BAR() { asm volatile("" ::: "memory"); __builtin_amdgcn_s_barrier(); asm volatile("" ::: "memory"); }
#define WAITL(n) { asm volatile("s_waitcnt lgkmcnt(" #n ")" ::: "memory"); __builtin_amdgcn_sched_barrier(0); }
#define WAITV(n) { asm volatile("s_waitcnt vmcnt(" #n ")" ::: "memory"); }

    const int NT = K >> 6;                    // K-tiles (>= 2 for all call sites)

    // ---- prologue: tile0 fully + {A0,B1,A1}(1) staged; vmcnt(6) retires tile0 exactly
    STAGE_B(0, 0, 0);
    STAGE_A(0, 0, 0);
    STAGE_B(0, 1, 0);
    STAGE_A(0, 1, 0);
    STAGE_A(1, 0, 64);
    STAGE_B(1, 1, 64);
    STAGE_A(1, 1, 64);
    WAITV(6);
    BAR();
    R_A0();                                   // tile0 A0 frags   (8 reads)
    R_B0();                                   // tile0 B0 frags   (4 reads)

    for (int s = 0; s < NT; s++) {
        const int b = s & 1, bn = b ^ 1;
        const int ks1 = (s + 1 < NT) ? (s + 1) * 64 : 0;   // dummy loads keep FIFO exact
        const int ks2 = (s + 2 < NT) ? (s + 2) * 64 : 0;

        // ---- p0: prefetch B1 frags; MFMA q00
        R_B1();                               // +4  (out: 16)
        STAGE_B(bn, 0, ks1);
        BAR();
        WAITL(4);                             // retire afA + bfr0 (12)
        MFMA16(afA, bfr0, 0, 0);
        BAR();
        // ---- p1: prefetch A1 frags; MFMA q01
        R_A1();                               // +8  (out: 12)
        STAGE_A(b, 0, ks2);
        BAR();
        WAITL(8);                             // retire bfr1 (4)
        MFMA16(afA, bfr1, 0, 1);
        BAR();
        // ---- p2: MFMA q11; then counted vmem wait gating next-tile frag reads
        STAGE_B(b, 1, ks2);
        BAR();
        WAITL(0);                             // retire afB (8)
        MFMA16(afB, bfr1, 1, 1);
        WAITV(4);                             // retires exactly tile s+1's 8 loads
        BAR();
        // ---- p3: next-tile A0/B0 frags from buffer bn; MFMA q10
        aH0 ^= 32768u; aH1 ^= 32768u; bH0 ^= 32768u; bH1 ^= 32768u;
        R_A0();                               // tile s+1 A0 (8)
        MFMA16(afB, bfr0, 1, 0);
        R_B0();                               // tile s+1 B0 (4)  (reg WAR only)
        STAGE_A(b, 1, ks2);
        BAR();
    }
    asm volatile("s_waitcnt vmcnt(0) lgkmcnt(0)" ::: "memory");  // drain tail dummies
    __builtin_amdgcn_sched_barrier(0);

    // ---- epilogue: v = acc (+ bias); epi==1 -> gelu; accumF -> +outF; residB -> +resid
    const int r0 = quad * 4;
    #pragma unroll
    for (int qm = 0; qm < 2; qm++)
    #pragma unroll
    for (int qn = 0; qn < 2; qn++)
    #pragma unroll
    for (int mf = 0; mf < 4; mf++)
    #pragma unroll
    for (int nf = 0; nf < 2; nf++) {
        int gn = n0 + qn * 128 + wc * 32 + nf * 16 + l15;
        float bv = bias ? bias[gn] : 0.0f;
        #pragma unroll
        for (int r = 0; r < 4; r++) {
            int gm = m0 + qm * 128 + wr * 64 + mf * 16 + r0 + r;
            float v = acc[qm][qn][mf][nf][r] + bv;
            if (epi == 1) v = fast_gelu(v);
            long long off = (long long)gm * N + gn;
            if (accumF) v += outF[off];
            if (residB) v += b2f(residB[off]);
            if (outF) outF[off] = v;
            if (outB) outB[off] = f2b(v);
        }
    }
#undef STAGE_A
#undef STAGE_B
#undef DSR
#undef R_A0
#undef R_A1
#undef R_B0
#undef R_B1
#undef MFMA16
#undef BAR
#undef WAITL
#undef WAITV
}

// ---------- windowed attention: one block per (b, window, head) ----------
// R6: LDS traffic vectorized 4x (ds_read_b128 everywhere). Per thread: ~550 b128 reads
// vs ~2200 scalar b32 before. Strides 68 floats (272 B: 16B-aligned; broadcast reads
// conflict-immune; per-lane q/p reads 8-way on stride-68 -- acceptable). pmax/psum
// alias dead ks space (extra sync before reuse). Staging: short8 global loads,
// float4 LDS writes. Output: short8 stores. LDS = 52.2 KB -> 3 blocks/CU.
typedef short short8 __attribute__((ext_vector_type(8)));
__global__ __launch_bounds__(256) void attn_kernel(const unsigned short* __restrict__ qkv,
                                                   unsigned short* __restrict__ o) {
    __shared__ float qs[64 * 68];   // Q, then probs
    __shared__ float ks[64 * 68];   // K; tail reused for pmax/psum after scores
    __shared__ float vs[64 * 68];   // V
    float* pmax = ks;               // 256 floats, aliased (sync-protected)
    float* psum = ks + 256;
    int blk = blockIdx.x;                 // b*16*12 + w*12 + h
    int h = blk % 12;
    int bw = blk / 12;
    int wi = bw % 16, b = bw / 16;
    int rowBase = b * 1024 + wi * 64;
    int tid = threadIdx.x;

    // ---- staging: thread handles row lr, 16-col chunk c0 (vectorized 8-wide)
    int lr = tid >> 2, c0 = (tid & 3) * 16;
    const unsigned short* src = qkv + (long long)(rowBase + lr) * 2304 + h * 64 + c0;
    #pragma unroll
    for (int half = 0; half < 2; half++) {
        short8 qv = *(const short8*)(src + half * 8);
        short8 kv = *(const short8*)(src + 768 + half * 8);
        short8 vv = *(const short8*)(src + 1536 + half * 8);
        #pragma unroll
        for (int q4 = 0; q4 < 2; q4++) {
            f32x4 qf, kf, vf;
            #pragma unroll
            for (int e = 0; e < 4; e++) {
                qf[e] = b2f((unsigned short)qv[q4 * 4 + e]);
                kf[e] = b2f((unsigned short)kv[q4 * 4 + e]);
                vf[e] = b2f((unsigned short)vv[q4 * 4 + e]);
            }
            int cc = c0 + half * 8 + q4 * 4;
            *(f32x4*)&qs[lr * 68 + cc] = qf;
            *(f32x4*)&ks[lr * 68 + cc] = kf;
            *(f32x4*)&vs[lr * 68 + cc] = vf;
        }
    }
    __syncthreads();

    int r = tid & 63, cg = tid >> 6;
    // ---- scores: svals[j] = sum_kk q[r][kk] * k[cg*16+j][kk], vectorized by 4
    float svals[16] = {};
    for (int kk4 = 0; kk4 < 16; kk4++) {
        f32x4 qv = *(const f32x4*)&qs[r * 68 + kk4 * 4];     // per-lane (8-way alias)
        #pragma unroll
        for (int j = 0; j < 16; j++) {
            f32x4 kv = *(const f32x4*)&ks[(cg * 16 + j) * 68 + kk4 * 4];  // broadcast
            svals[j] += qv[0] * kv[0] + qv[1] * kv[1] + qv[2] * kv[2] + qv[3] * kv[3];
        }
    }
    float smax = -1e30f;
    #pragma unroll
    for (int j = 0; j < 16; j++) {
        svals[j] *= 0.125f;
        smax = fmaxf(smax, svals[j]);
    }
    __syncthreads();   // all ks reads done -> pmax/psum may alias ks; all qs(Q) reads done
    pmax[cg * 64 + r] = smax;
    __syncthreads();
    float m = fmaxf(fmaxf(pmax[r], pmax[64 + r]), fmaxf(pmax[128 + r], pmax[192 + r]));
    float lsum = 0.0f;
    #pragma unroll
    for (int j = 0; j < 16; j++) {
        float e = __expf(svals[j] - m);
        qs[r * 68 + cg * 16 + j] = e;     // probs into qs
        lsum += e;
    }
    psum[cg * 64 + r] = lsum;
    __syncthreads();
    float inv = __builtin_amdgcn_rcpf(psum[r] + psum[64 + r] + psum[128 + r] + psum[192 + r]);

    // ---- PV: oacc[j] = sum_c p[r][c] * v[c][cg*16+j], vectorized by 4 in c and j
    float oacc[16] = {};
    for (int c4 = 0; c4 < 16; c4++) {
        f32x4 pv = *(const f32x4*)&qs[r * 68 + c4 * 4];      // per-lane probs
        #pragma unroll
        for (int j4 = 0; j4 < 4; j4++) {
            f32x4 v0 = *(const f32x4*)&vs[(c4 * 4 + 0) * 68 + cg * 16 + j4 * 4];  // broadcast
            f32x4 v1 = *(const f32x4*)&vs[(c4 * 4 + 1) * 68 + cg * 16 + j4 * 4];
            f32x4 v2 = *(const f32x4*)&vs[(c4 * 4 + 2) * 68 + cg * 16 + j4 * 4];
            f32x4 v3 = *(const f32x4*)&vs[(c4 * 4 + 3) * 68 + cg * 16 + j4 * 4];
            #pragma unroll
            for (int e = 0; e < 4; e++)
                oacc[j4 * 4 + e] += pv[0] * v0[e] + pv[1] * v1[e] + pv[2] * v2[e] + pv[3] * v3[e];
        }
    }
    unsigned short* dst = o + (long long)(rowBase + r) * 768 + h * 64 + cg * 16;
    #pragma unroll
    for (int half = 0; half < 2; half++) {
        short8 ov;
        #pragma unroll
        for (int e = 0; e < 8; e++) ov[e] = (short)f2b(oacc[half * 8 + e] * inv);
        *(short8*)(dst + half * 8) = ov;
    }
}

extern "C" void kernel_launch(void* const* d_in, const int* in_sizes, int n_in,
                              void* d_out, int out_size, void* d_ws, size_t ws_size,
                              hipStream_t stream) {
    const float* input   = (const float*)d_in[0];
    const float* patch_w = (const float*)d_in[1];
    const float* patch_b = (const float*)d_in[2];
    const float* ln_g    = (const float*)d_in[3];
    const float* ln_b    = (const float*)d_in[4];
    const float* qkv_w   = (const float*)d_in[5];
    const float* qkv_b   = (const float*)d_in[6];
    const float* proj_w  = (const float*)d_in[7];
    const float* proj_b  = (const float*)d_in[8];
    const float* ff1_w   = (const float*)d_in[9];
    const float* ff1_b   = (const float*)d_in[10];
    const float* ff2_w   = (const float*)d_in[11];
    const float* ff2_b   = (const float*)d_in[12];
    float* out = (float*)d_out;

    const int MN = 16384;   // B*N tokens
    const int D = 768, F = 3072, TD = 2304;
    const int NY = MN / 256;  // 64 row-blocks (divisible by 8)

    // ---- workspace layout: 83,165,184 uint16 = 166.33 MB (proven to fit) ----
    unsigned short* wPatch = (unsigned short*)d_ws;            // (768,768)
    unsigned short* wQkvT  = wPatch + 589824;                  // (2304,768)
    unsigned short* wProjT = wQkvT + 1769472;                  // (768,768)
    unsigned short* wFf1T  = wProjT + 589824;                  // (3072,768)
    unsigned short* wFf2T  = wFf1T + 2359296;                  // (768,3072)
    unsigned short* bigBuf = wFf2T + 2359296;                  // 50331648: im2col -> h -> qkv -> h2
    unsigned short* xid    = bigBuf + 50331648;                // 12582912: identity -> x2 bf16
    unsigned short* t0     = xid + 12582912;                   // 12582912: y / o bf16
    // d_out (f32, 16384x768): xe (patch GEMM -> LN), then final output

    // ---- weight prep ----
    convert_bf16_kernel<<<(589824 + 255) / 256, 256, 0, stream>>>(patch_w, wPatch, 589824);
    transpose_to_bf16_kernel<<<(1769472 + 255) / 256, 256, 0, stream>>>(qkv_w, wQkvT, D, TD);
    transpose_to_bf16_kernel<<<(589824 + 255) / 256, 256, 0, stream>>>(proj_w, wProjT, D, D);
    transpose_to_bf16_kernel<<<(2359296 + 255) / 256, 256, 0, stream>>>(ff1_w, wFf1T, D, F);
    transpose_to_bf16_kernel<<<(2359296 + 255) / 256, 256, 0, stream>>>(ff2_w, wFf2T, F, D);

    // ---- pipeline ----
    im2col_kernel<<<(MN * 768) / 256, 256, 0, stream>>>(input, bigBuf);

    // G1: xe = im2col @ patch_w^T + patch_b  -> d_out (f32)
    gemm256_kernel<<<(D / 256) * NY, 512, 0, stream>>>(bigBuf, wPatch, patch_b, nullptr,
                                                       out, nullptr, MN, D, 768, 768, 0, 0);
    // LN + PE -> xid (bf16 identity + GEMM input)
    ln_pe_kernel<<<MN, 256, 0, stream>>>(out, ln_g, ln_b, xid);

    // FF#1: h = gelu(xid @ ff1 + b1) -> bigBuf (bf16, 100.7 MB)
    gemm256_kernel<<<(F / 256) * NY, 512, 0, stream>>>(xid, wFf1T, ff1_b, nullptr,
                                                       nullptr, bigBuf, MN, F, 768, 768, 1, 0);
    // y = h @ ff2 + b2 -> t0 (bf16)
    gemm256_kernel<<<(D / 256) * NY, 512, 0, stream>>>(bigBuf, wFf2T, ff2_b, nullptr,
                                                       nullptr, t0, MN, D, F, F, 0, 0);
    // qkv = y @ qkv_w + qkv_b -> bigBuf (bf16, 75.5 MB; h dead)
    gemm256_kernel<<<(TD / 256) * NY, 512, 0, stream>>>(t0, wQkvT, qkv_b, nullptr,
                                                        nullptr, bigBuf, MN, TD, 768, 768, 0, 0);
    // attention -> o (bf16) into t0
    attn_kernel<<<16 * 16 * 12, 256, 0, stream>>>(bigBuf, t0);

    // x2 = o @ proj + proj_b + identity(xid) -> xid (bf16; in-place per-element safe)
    gemm256_kernel<<<(D / 256) * NY, 512, 0, stream>>>(t0, wProjT, proj_b, xid,
                                                       nullptr, xid, MN, D, 768, 768, 0, 0);

    // FF#2: h2 = gelu(x2 @ ff1 + b1) -> bigBuf (qkv dead)
    gemm256_kernel<<<(F / 256) * NY, 512, 0, stream>>>(xid, wFf1T, ff1_b, nullptr,
                                                       nullptr, bigBuf, MN, F, 768, 768, 1, 0);
    // out = h2 @ ff2 + b2 + x2(bf16 resid)  (f32, final)
    gemm256_kernel<<<(D / 256) * NY, 512, 0, stream>>>(bigBuf, wFf2T, ff2_b, xid,
                                                       out, nullptr, MN, D, F, F, 0, 0);
}

// Round 7
// 892.252 us; speedup vs baseline: 2.2569x; 1.0025x over previous
//
#include <hip/hip_runtime.h>

typedef unsigned int uint;
typedef short bf16x8 __attribute__((ext_vector_type(8)));
typedef float f32x4 __attribute__((ext_vector_type(4)));
typedef short short8 __attribute__((ext_vector_type(8)));

// ---------- bf16 helpers (bit-level, RNE) ----------
__device__ __forceinline__ unsigned short f2b(float f) {
    uint u = __builtin_bit_cast(uint, f);
    u += 0x7fffu + ((u >> 16) & 1u);
    return (unsigned short)(u >> 16);
}
__device__ __forceinline__ float b2f(unsigned short h) {
    uint u = ((uint)h) << 16;
    return __builtin_bit_cast(float, u);
}

// ---------- fast tanh-gelu ----------
__device__ __forceinline__ float fast_gelu(float v) {
    float s  = v * v;
    float t2 = __builtin_fmaf(0.044715f * s, v, v);     // v + 0.044715 v^3
    float e  = __expf(-1.5957691216f * t2);             // exp(-2*0.79788456*t2)
    return v * __builtin_amdgcn_rcpf(1.0f + e);
}

// ---------- async global->LDS, 16B per lane (wave-uniform LDS base + lane*16) ----------
__device__ __forceinline__ void gl_lds16(const unsigned short* g, unsigned short* l) {
    __builtin_amdgcn_global_load_lds(
        reinterpret_cast<const __attribute__((address_space(1))) unsigned int*>(
            reinterpret_cast<uintptr_t>(g)),
        reinterpret_cast<__attribute__((address_space(3))) unsigned int*>(
            reinterpret_cast<uintptr_t>(l)),
        16, 0, 0);
}

// ---------- weight prep ----------
__global__ __launch_bounds__(256) void convert_bf16_kernel(const float* __restrict__ src,
                                                           unsigned short* __restrict__ dst, int n) {
    int idx = blockIdx.x * 256 + threadIdx.x;
    if (idx < n) dst[idx] = f2b(src[idx]);
}

// src is (K, N) row-major; dst is (N, K) row-major (i.e. B^T), bf16.
__global__ __launch_bounds__(256) void transpose_to_bf16_kernel(const float* __restrict__ src,
                                                                unsigned short* __restrict__ dst,
                                                                int K, int N) {
    long long idx = (long long)blockIdx.x * 256 + threadIdx.x;
    if (idx >= (long long)K * N) return;
    int k = (int)(idx / N);
    int n = (int)(idx % N);
    dst[(long long)n * K + k] = f2b(src[idx]);
}

// ---------- LayerNorm + sinusoidal PE -> bf16 ----------
__global__ __launch_bounds__(256) void ln_pe_kernel(const float* __restrict__ xe,
                                                    const float* __restrict__ g,
                                                    const float* __restrict__ bb,
                                                    unsigned short* __restrict__ xb) {
    int row = blockIdx.x;            // 0..16383
    int pos = row & 1023;
    const float* xr = xe + (long long)row * 768;
    float v0 = xr[threadIdx.x];
    float v1 = xr[threadIdx.x + 256];
    float v2 = xr[threadIdx.x + 512];
    float s = v0 + v1 + v2;
    float sq = v0 * v0 + v1 * v1 + v2 * v2;
    for (int o = 32; o > 0; o >>= 1) {
        s  += __shfl_down(s, o, 64);
        sq += __shfl_down(sq, o, 64);
    }
    __shared__ float ps[4], pq[4];
    int w = threadIdx.x >> 6, lane = threadIdx.x & 63;
    if (lane == 0) { ps[w] = s; pq[w] = sq; }
    __syncthreads();
    float ts = ps[0] + ps[1] + ps[2] + ps[3];
    float tq = pq[0] + pq[1] + pq[2] + pq[3];
    float mean = ts * (1.0f / 768.0f);
    float var  = tq * (1.0f / 768.0f) - mean * mean;
    float inv  = rsqrtf(var + 1e-5f);
    #pragma unroll
    for (int dd = 0; dd < 3; dd++) {
        int d = threadIdx.x + dd * 256;
        float val = (dd == 0) ? v0 : (dd == 1) ? v1 : v2;
        float y = (val - mean) * inv * g[d] + bb[d];
        float freq = __expf(-(float)(d & ~1) * (9.210340371976184f / 768.0f));
        float ang = (float)pos * freq;
        y += (d & 1) ? cosf(ang) : sinf(ang);
        xb[(long long)row * 768 + d] = f2b(y);
    }
}

// ---------- fused im2col + patch GEMM: out(16384,768) = im2col(input) @ patch_w^T + b ----------
// A is never materialized: each staging thread's 8 k-elements (k = c*256+p*16+q, q-half)
// are 8 CONTIGUOUS floats of input -> two aligned f32x4 loads + cvt + one ds_write_b128
// into the XOR-swizzled linear slot. B staged via global_load_lds. Single-buffered
// drain schedule (__syncthreads handles all counters). Fragment geometry identical to
// gemm256 (swizzle-verified). Saves the im2col kernel + its 25MB write + re-read.
__global__ __launch_bounds__(512) void gemm_patch_kernel(const float* __restrict__ input,
                                                         const unsigned short* __restrict__ BT,
                                                         const float* __restrict__ bias,
                                                         float* __restrict__ outF) {
    __shared__ __align__(16) unsigned short As[256 * 64];   // 32 KB
    __shared__ __align__(16) unsigned short Bs[256 * 64];   // 32 KB
    const int N = 768, K = 768, ldb = 768;

    // ---- XCD swizzle (nwg=192, 192%8==0: bijective)
    const int nX = 3;
    int id = blockIdx.x;
    int xcd = id & 7;
    int sq_ = id >> 3;
    int bx = sq_ % nX;
    int by = (sq_ / nX) * 8 + xcd;
    const int m0 = by * 256, n0 = bx * 256;

    const int tid = threadIdx.x;
    const int w = tid >> 6, lane = tid & 63;
    const int wr = w >> 2, wc = w & 3;               // 2x4 wave grid
    const int quad = lane >> 4, l15 = lane & 15;
    const int swz = l15 & 7;

    // ---- staging ids: thread t -> LDS 16B-unit t; fetches swizzled global col gc8
    const int row0 = tid >> 3;                       // 0..63
    const int c8   = tid & 7;
    const int gc8  = c8 ^ (row0 & 7);
    const unsigned short* Bg = BT + (long long)(n0 + row0) * ldb + gc8 * 8;
    unsigned short* Ad = As + row0 * 64 + c8 * 8;
    unsigned short* Bd = Bs + row0 * 64 + c8 * 8;

    // token coords for this thread's 4 A-rows (rows m0+row0+hh*64)
    int nb[4], nhp[4], nwp[4];
    #pragma unroll
    for (int hh = 0; hh < 4; hh++) {
        int n = m0 + row0 + hh * 64;
        nb[hh] = n >> 10;
        int t = n & 1023;
        nhp[hh] = t >> 5;
        nwp[hh] = t & 31;
    }

    f32x4 acc[2][2][4][2] = {};

    for (int k0 = 0; k0 < K; k0 += 64) {
        __syncthreads();                           // previous tile's LDS reads done
        // ---- A staging: fused im2col (k = c*256 + p*16 + q; 8 elems = contiguous W-run)
        int k = k0 + gc8 * 8;
        int c = k >> 8, rm = k & 255;
        int p = rm >> 4, q = rm & 15;              // q in {0, 8}
        #pragma unroll
        for (int hh = 0; hh < 4; hh++) {
            const float* s = input +
                ((((long long)nb[hh] * 3 + c) * 512) + nhp[hh] * 16 + p) * 512 + nwp[hh] * 16 + q;
            f32x4 f0 = *(const f32x4*)s;
            f32x4 f1 = *(const f32x4*)(s + 4);
            bf16x8 v;
            #pragma unroll
            for (int e = 0; e < 4; e++) {
                v[e]     = (short)f2b(f0[e]);
                v[4 + e] = (short)f2b(f1[e]);
            }
            *(bf16x8*)(Ad + hh * 4096) = v;
        }
        // ---- B staging: async global->LDS (4 x 64-row chunks)
        gl_lds16(Bg + k0, Bd);
        gl_lds16(Bg + k0 + (long long)64 * ldb,  Bd + 4096);
        gl_lds16(Bg + k0 + (long long)128 * ldb, Bd + 8192);
        gl_lds16(Bg + k0 + (long long)192 * ldb, Bd + 12288);
        __syncthreads();                           // drains lgkm (A writes) + vmcnt (B)

        // ---- compute: same fragment geometry as gemm256 (compiler-scheduled reads)
        #pragma unroll
        for (int qm = 0; qm < 2; qm++) {
            bf16x8 af[4][2];
            #pragma unroll
            for (int mf = 0; mf < 4; mf++)
                #pragma unroll
                for (int kh = 0; kh < 2; kh++)
                    af[mf][kh] = *(const bf16x8*)(As + (qm * 128 + wr * 64 + mf * 16 + l15) * 64
                                                  + (((kh * 4 + quad) ^ swz) * 8));
            #pragma unroll
            for (int qn = 0; qn < 2; qn++) {
                bf16x8 bf[2][2];
                #pragma unroll
                for (int nf = 0; nf < 2; nf++)
                    #pragma unroll
                    for (int kh = 0; kh < 2; kh++)
                        bf[nf][kh] = *(const bf16x8*)(Bs + (qn * 128 + wc * 32 + nf * 16 + l15) * 64
                                                      + (((kh * 4 + quad) ^ swz) * 8));
                #pragma unroll
                for (int mf = 0; mf < 4; mf++)
                    #pragma unroll
                    for (int nf = 0; nf < 2; nf++) {
                        acc[qm][qn][mf][nf] = __builtin_amdgcn_mfma_f32_16x16x32_bf16(
                            af[mf][0], bf[nf][0], acc[qm][qn][mf][nf], 0, 0, 0);
                        acc[qm][qn][mf][nf] = __builtin_amdgcn_mfma_f32_16x16x32_bf16(
                            af[mf][1], bf[nf][1], acc[qm][qn][mf][nf], 0, 0, 0);
                    }
            }
        }
    }

    // ---- epilogue: bias + f32 store
    const int r0 = quad * 4;
    #pragma unroll
    for (int qm = 0; qm < 2; qm++)
    #pragma unroll
    for (int qn = 0; qn < 2; qn++)
    #pragma unroll
    for (int mf = 0; mf < 4; mf++)
    #pragma unroll
    for (int nf = 0; nf < 2; nf++) {
        int gn = n0 + qn * 128 + wc * 32 + nf * 16 + l15;
        float bv = bias[gn];
        #pragma unroll
        for (int r = 0; r < 4; r++) {
            int gm = m0 + qm * 128 + wr * 64 + mf * 16 + r0 + r;
            outF[(long long)gm * N + gn] = acc[qm][qn][mf][nf][r] + bv;
        }
    }
}

// ---------- 256x256 bf16 MFMA GEMM, BK=64, 4-phase counted-vmcnt/lgkmcnt pipeline ----------
// (R3 structure, frozen: 4 schedule variants measured within session noise; register file
// is the structural cap at 2 waves/SIMD. setprio REMOVED per m190 evidence (negative on
// non-8-phase GEMM).) All fragment LDS loads are inline-asm ds_read_b128 (invisible to
// SIInsertWaitcnts); counted lgkm one phase ahead; vmcnt(4) once per K-tile.
__global__ __launch_bounds__(512) void gemm256_kernel(const unsigned short* __restrict__ A,
                                                      const unsigned short* __restrict__ BT,
                                                      const float* __restrict__ bias,
                                                      const unsigned short* __restrict__ residB,
                                                      float* __restrict__ outF,
                                                      unsigned short* __restrict__ outB,
                                                      int M, int N, int K, int ldb,
                                                      int epi, int accumF) {
    __shared__ __align__(16) unsigned short As[2][256 * 64];   // 64 KB
    __shared__ __align__(16) unsigned short Bs[2][256 * 64];   // 64 KB

    const int nX = N >> 8;                    // N/256
    int id = blockIdx.x;
    int xcd = id & 7;
    int sq_ = id >> 3;
    int bx = sq_ % nX;
    int by = (sq_ / nX) * 8 + xcd;
    const int m0 = by * 256, n0 = bx * 256;

    const int tid = threadIdx.x;
    const int w = tid >> 6, lane = tid & 63;
    const int wr = w >> 2, wc = w & 3;               // 2x4 wave grid
    const int quad = lane >> 4, l15 = lane & 15;
    const int swz = l15 & 7;

    const int row0 = tid >> 3;                       // 0..63
    const int c8   = tid & 7;
    const int gc8  = c8 ^ (row0 & 7);
    const unsigned short* Ag = A  + (long long)(m0 + row0) * K   + gc8 * 8;
    const unsigned short* Bg = BT + (long long)(n0 + row0) * ldb + gc8 * 8;
    unsigned short* Ad = &As[0][0] + row0 * 64 + c8 * 8;
    unsigned short* Bd = &Bs[0][0] + row0 * 64 + c8 * 8;
    const long long aK64 = (long long)64 * K,  aK128 = (long long)128 * K;
    const long long bL64 = (long long)64 * ldb, bL128 = (long long)128 * ldb;

#define STAGE_A(bsel, h, ks) { \
    const unsigned short* s_ = Ag + (h) * aK128 + (ks); \
    unsigned short* d_ = Ad + (bsel) * 16384 + (h) * 8192; \
    gl_lds16(s_, d_); gl_lds16(s_ + aK64, d_ + 4096); }
#define STAGE_B(bsel, h, ks) { \
    const unsigned short* s_ = Bg + (h) * bL128 + (ks); \
    unsigned short* d_ = Bd + (bsel) * 16384 + (h) * 8192; \
    gl_lds16(s_, d_); gl_lds16(s_ + bL64, d_ + 4096); }

    unsigned asB = (unsigned)(uintptr_t)(&As[0][0]);
    unsigned bsB = (unsigned)(uintptr_t)(&Bs[0][0]);
    unsigned aH0 = asB + (unsigned)((wr * 64 + l15) * 128 + ((quad ^ swz) * 16));
    unsigned aH1 = asB + (unsigned)((wr * 64 + l15) * 128 + (((4 + quad) ^ swz) * 16));
    unsigned bH0 = bsB + (unsigned)((wc * 32 + l15) * 128 + ((quad ^ swz) * 16));
    unsigned bH1 = bsB + (unsigned)((wc * 32 + l15) * 128 + (((4 + quad) ^ swz) * 16));

    bf16x8 afA[4][2], afB[4][2], bfr0[2][2], bfr1[2][2];
    f32x4 acc[2][2][4][2] = {};

#define DSR(dst, addr, IMM) \
    asm volatile("ds_read_b128 %0, %1 offset:%2" : "=&v"(dst) : "v"(addr), "i"(IMM))

#define R_A0() { DSR(afA[0][0], aH0, 0);     DSR(afA[1][0], aH0, 2048); \
                 DSR(afA[2][0], aH0, 4096);  DSR(afA[3][0], aH0, 6144); \
                 DSR(afA[0][1], aH1, 0);     DSR(afA[1][1], aH1, 2048); \
                 DSR(afA[2][1], aH1, 4096);  DSR(afA[3][1], aH1, 6144); }
#define R_A1() { DSR(afB[0][0], aH0, 16384); DSR(afB[1][0], aH0, 18432); \
                 DSR(afB[2][0], aH0, 20480); DSR(afB[3][0], aH0, 22528); \
                 DSR(afB[0][1], aH1, 16384); DSR(afB[1][1], aH1, 18432); \
                 DSR(afB[2][1], aH1, 20480); DSR(afB[3][1], aH1, 22528); }
#define R_B0() { DSR(bfr0[0][0], bH0, 0);     DSR(bfr0[1][0], bH0, 2048); \
                 DSR(bfr0[0][1], bH1, 0);     DSR(bfr0[1][1], bH1, 2048); }
#define R_B1() { DSR(bfr1[0][0], bH0, 16384); DSR(bfr1[1][0], bH0, 18432); \
                 DSR(bfr1[0][1], bH1, 16384); DSR(bfr1[1][1], bH1, 18432); }

#define MFMA16(AF, BF, qm, qn) { \
    __builtin_amdgcn_sched_barrier(0); \
    _Pragma("unroll") for (int mf_ = 0; mf_ < 4; mf_++) \
    _Pragma("unroll") for (int nf_ = 0; nf_ < 2; nf_++) { \
      acc[qm][qn][mf_][nf_] = __builtin_amdgcn_mfma_f32_16x16x32_bf16(AF[mf_][0], BF[nf_][0], acc[qm][qn][mf_][nf_], 0, 0, 0); \
      acc[qm][qn][mf_][nf_] = __builtin_amdgcn_mfma_f32_16x16x32_bf16(AF[mf_][1], BF[nf_][1], acc[qm][qn][mf_][nf_], 0, 0, 0); \
    } \
    __builtin_amdgcn_sched_barrier(0); }

#define BAR() { asm volatile("" ::: "memory"); __builtin_amdgcn_s_barrier(); asm volatile("" ::: "memory"); }
#define WAITL(n) { asm volatile("s_waitcnt lgkmcnt(" #n ")" ::: "memory"); __builtin_amdgcn_sched_barrier(0); }
#define WAITV(n) { asm volatile("s_waitcnt vmcnt(" #n ")" ::: "memory"); }

    const int NT = K >> 6;

    STAGE_B(0, 0, 0);
    STAGE_A(0, 0, 0);
    STAGE_B(0, 1, 0);
    STAGE_A(0, 1, 0);
    STAGE_A(1, 0, 64);
    STAGE_B(1, 1, 64);
    STAGE_A(1, 1, 64);
    WAITV(6);
    BAR();
    R_A0();
    R_B0();

    for (int s = 0; s < NT; s++) {
        const int b = s & 1, bn = b ^ 1;
        const int ks1 = (s + 1 < NT) ? (s + 1) * 64 : 0;
        const int ks2 = (s + 2 < NT) ? (s + 2) * 64 : 0;

        R_B1();
        STAGE_B(bn, 0, ks1);
        BAR();
        WAITL(4);
        MFMA16(afA, bfr0, 0, 0);
        BAR();
        R_A1();
        STAGE_A(b, 0, ks2);
        BAR();
        WAITL(8);
        MFMA16(afA, bfr1, 0, 1);
        BAR();
        STAGE_B(b, 1, ks2);
        BAR();
        WAITL(0);
        MFMA16(afB, bfr1, 1, 1);
        WAITV(4);
        BAR();
        aH0 ^= 32768u; aH1 ^= 32768u; bH0 ^= 32768u; bH1 ^= 32768u;
        R_A0();
        MFMA16(afB, bfr0, 1, 0);
        R_B0();
        STAGE_A(b, 1, ks2);
        BAR();
    }
    asm volatile("s_waitcnt vmcnt(0) lgkmcnt(0)" ::: "memory");
    __builtin_amdgcn_sched_barrier(0);

    const int r0 = quad * 4;
    #pragma unroll
    for (int qm = 0; qm < 2; qm++)
    #pragma unroll
    for (int qn = 0; qn < 2; qn++)
    #pragma unroll
    for (int mf = 0; mf < 4; mf++)
    #pragma unroll
    for (int nf = 0; nf < 2; nf++) {
        int gn = n0 + qn * 128 + wc * 32 + nf * 16 + l15;
        float bv = bias ? bias[gn] : 0.0f;
        #pragma unroll
        for (int r = 0; r < 4; r++) {
            int gm = m0 + qm * 128 + wr * 64 + mf * 16 + r0 + r;
            float v = acc[qm][qn][mf][nf][r] + bv;
            if (epi == 1) v = fast_gelu(v);
            long long off = (long long)gm * N + gn;
            if (accumF) v += outF[off];
            if (residB) v += b2f(residB[off]);
            if (outF) outF[off] = v;
            if (outB) outB[off] = f2b(v);
        }
    }
#undef STAGE_A
#undef STAGE_B
#undef DSR
#undef R_A0
#undef R_A1
#undef R_B0
#undef R_B1
#undef MFMA16
#undef BAR
#undef WAITL
#undef WAITV
}

// ---------- windowed attention: one block per (b, window, head) ----------
// Vectorized LDS traffic (ds_read_b128 everywhere); strides 68 floats; pmax/psum
// alias dead ks space (sync-protected). Staging short8 loads / f32x4 LDS writes.
__global__ __launch_bounds__(256) void attn_kernel(const unsigned short* __restrict__ qkv,
                                                   unsigned short* __restrict__ o) {
    __shared__ float qs[64 * 68];   // Q, then probs
    __shared__ float ks[64 * 68];   // K; head reused for pmax/psum after scores
    __shared__ float vs[64 * 68];   // V
    float* pmax = ks;
    float* psum = ks + 256;
    int blk = blockIdx.x;                 // b*16*12 + w*12 + h
    int h = blk % 12;
    int bw = blk / 12;
    int wi = bw % 16, b = bw / 16;
    int rowBase = b * 1024 + wi * 64;
    int tid = threadIdx.x;

    int lr = tid >> 2, c0 = (tid & 3) * 16;
    const unsigned short* src = qkv + (long long)(rowBase + lr) * 2304 + h * 64 + c0;
    #pragma unroll
    for (int half = 0; half < 2; half++) {
        short8 qv = *(const short8*)(src + half * 8);
        short8 kv = *(const short8*)(src + 768 + half * 8);
        short8 vv = *(const short8*)(src + 1536 + half * 8);
        #pragma unroll
        for (int q4 = 0; q4 < 2; q4++) {
            f32x4 qf, kf, vf;
            #pragma unroll
            for (int e = 0; e < 4; e++) {
                qf[e] = b2f((unsigned short)qv[q4 * 4 + e]);
                kf[e] = b2f((unsigned short)kv[q4 * 4 + e]);
                vf[e] = b2f((unsigned short)vv[q4 * 4 + e]);
            }
            int cc = c0 + half * 8 + q4 * 4;
            *(f32x4*)&qs[lr * 68 + cc] = qf;
            *(f32x4*)&ks[lr * 68 + cc] = kf;
            *(f32x4*)&vs[lr * 68 + cc] = vf;
        }
    }
    __syncthreads();

    int r = tid & 63, cg = tid >> 6;
    float svals[16] = {};
    for (int kk4 = 0; kk4 < 16; kk4++) {
        f32x4 qv = *(const f32x4*)&qs[r * 68 + kk4 * 4];
        #pragma unroll
        for (int j = 0; j < 16; j++) {
            f32x4 kv = *(const f32x4*)&ks[(cg * 16 + j) * 68 + kk4 * 4];
            svals[j] += qv[0] * kv[0] + qv[1] * kv[1] + qv[2] * kv[2] + qv[3] * kv[3];
        }
    }
    float smax = -1e30f;
    #pragma unroll
    for (int j = 0; j < 16; j++) {
        svals[j] *= 0.125f;
        smax = fmaxf(smax, svals[j]);
    }
    __syncthreads();
    pmax[cg * 64 + r] = smax;
    __syncthreads();
    float m = fmaxf(fmaxf(pmax[r], pmax[64 + r]), fmaxf(pmax[128 + r], pmax[192 + r]));
    float lsum = 0.0f;
    #pragma unroll
    for (int j = 0; j < 16; j++) {
        float e = __expf(svals[j] - m);
        qs[r * 68 + cg * 16 + j] = e;
        lsum += e;
    }
    psum[cg * 64 + r] = lsum;
    __syncthreads();
    float inv = __builtin_amdgcn_rcpf(psum[r] + psum[64 + r] + psum[128 + r] + psum[192 + r]);

    float oacc[16] = {};
    for (int c4 = 0; c4 < 16; c4++) {
        f32x4 pv = *(const f32x4*)&qs[r * 68 + c4 * 4];
        #pragma unroll
        for (int j4 = 0; j4 < 4; j4++) {
            f32x4 v0 = *(const f32x4*)&vs[(c4 * 4 + 0) * 68 + cg * 16 + j4 * 4];
            f32x4 v1 = *(const f32x4*)&vs[(c4 * 4 + 1) * 68 + cg * 16 + j4 * 4];
            f32x4 v2 = *(const f32x4*)&vs[(c4 * 4 + 2) * 68 + cg * 16 + j4 * 4];
            f32x4 v3 = *(const f32x4*)&vs[(c4 * 4 + 3) * 68 + cg * 16 + j4 * 4];
            #pragma unroll
            for (int e = 0; e < 4; e++)
                oacc[j4 * 4 + e] += pv[0] * v0[e] + pv[1] * v1[e] + pv[2] * v2[e] + pv[3] * v3[e];
        }
    }
    unsigned short* dst = o + (long long)(rowBase + r) * 768 + h * 64 + cg * 16;
    #pragma unroll
    for (int half = 0; half < 2; half++) {
        short8 ov;
        #pragma unroll
        for (int e = 0; e < 8; e++) ov[e] = (short)f2b(oacc[half * 8 + e] * inv);
        *(short8*)(dst + half * 8) = ov;
    }
}

extern "C" void kernel_launch(void* const* d_in, const int* in_sizes, int n_in,
                              void* d_out, int out_size, void* d_ws, size_t ws_size,
                              hipStream_t stream) {
    const float* input   = (const float*)d_in[0];
    const float* patch_w = (const float*)d_in[1];
    const float* patch_b = (const float*)d_in[2];
    const float* ln_g    = (const float*)d_in[3];
    const float* ln_b    = (const float*)d_in[4];
    const float* qkv_w   = (const float*)d_in[5];
    const float* qkv_b   = (const float*)d_in[6];
    const float* proj_w  = (const float*)d_in[7];
    const float* proj_b  = (const float*)d_in[8];
    const float* ff1_w   = (const float*)d_in[9];
    const float* ff1_b   = (const float*)d_in[10];
    const float* ff2_w   = (const float*)d_in[11];
    const float* ff2_b   = (const float*)d_in[12];
    float* out = (float*)d_out;

    const int MN = 16384;   // B*N tokens
    const int D = 768, F = 3072, TD = 2304;
    const int NY = MN / 256;  // 64 row-blocks (divisible by 8)

    // ---- workspace layout ----
    unsigned short* wPatch = (unsigned short*)d_ws;            // (768,768)
    unsigned short* wQkvT  = wPatch + 589824;                  // (2304,768)
    unsigned short* wProjT = wQkvT + 1769472;                  // (768,768)
    unsigned short* wFf1T  = wProjT + 589824;                  // (3072,768)
    unsigned short* wFf2T  = wFf1T + 2359296;                  // (768,3072)
    unsigned short* bigBuf = wFf2T + 2359296;                  // 50331648: h -> qkv -> h2
    unsigned short* xid    = bigBuf + 50331648;                // 12582912: identity -> x2 bf16
    unsigned short* t0     = xid + 12582912;                   // 12582912: y / o bf16

    // ---- weight prep ----
    convert_bf16_kernel<<<(589824 + 255) / 256, 256, 0, stream>>>(patch_w, wPatch, 589824);
    transpose_to_bf16_kernel<<<(1769472 + 255) / 256, 256, 0, stream>>>(qkv_w, wQkvT, D, TD);
    transpose_to_bf16_kernel<<<(589824 + 255) / 256, 256, 0, stream>>>(proj_w, wProjT, D, D);
    transpose_to_bf16_kernel<<<(2359296 + 255) / 256, 256, 0, stream>>>(ff1_w, wFf1T, D, F);
    transpose_to_bf16_kernel<<<(2359296 + 255) / 256, 256, 0, stream>>>(ff2_w, wFf2T, F, D);

    // ---- pipeline ----
    // G1 (fused im2col): xe = im2col(input) @ patch_w^T + patch_b -> d_out (f32)
    gemm_patch_kernel<<<(D / 256) * NY, 512, 0, stream>>>(input, wPatch, patch_b, out);
    // LN + PE -> xid (bf16 identity + GEMM input)
    ln_pe_kernel<<<MN, 256, 0, stream>>>(out, ln_g, ln_b, xid);

    // FF#1: h = gelu(xid @ ff1 + b1) -> bigBuf
    gemm256_kernel<<<(F / 256) * NY, 512, 0, stream>>>(xid, wFf1T, ff1_b, nullptr,
                                                       nullptr, bigBuf, MN, F, 768, 768, 1, 0);
    // y = h @ ff2 + b2 -> t0 (bf16)
    gemm256_kernel<<<(D / 256) * NY, 512, 0, stream>>>(bigBuf, wFf2T, ff2_b, nullptr,
                                                       nullptr, t0, MN, D, F, F, 0, 0);
    // qkv = y @ qkv_w + qkv_b -> bigBuf
    gemm256_kernel<<<(TD / 256) * NY, 512, 0, stream>>>(t0, wQkvT, qkv_b, nullptr,
                                                        nullptr, bigBuf, MN, TD, 768, 768, 0, 0);
    // attention -> o (bf16) into t0
    attn_kernel<<<16 * 16 * 12, 256, 0, stream>>>(bigBuf, t0);

    // x2 = o @ proj + proj_b + identity(xid) -> xid
    gemm256_kernel<<<(D / 256) * NY, 512, 0, stream>>>(t0, wProjT, proj_b, xid,
                                                       nullptr, xid, MN, D, 768, 768, 0, 0);

    // FF#2: h2 = gelu(x2 @ ff1 + b1) -> bigBuf
    gemm256_kernel<<<(F / 256) * NY, 512, 0, stream>>>(xid, wFf1T, ff1_b, nullptr,
                                                       nullptr, bigBuf, MN, F, 768, 768, 1, 0);
    // out = h2 @ ff2 + b2 + x2(bf16 resid)  (f32, final)
    gemm256_kernel<<<(D / 256) * NY, 512, 0, stream>>>(bigBuf, wFf2T, ff2_b, xid,
                                                       out, nullptr, MN, D, F, F, 0, 0);
}